// Round 4
// baseline (388.786 us; speedup 1.0000x reference)
//
#include <hip/hip_runtime.h>

typedef __attribute__((ext_vector_type(4))) float f32x4;
typedef __attribute__((ext_vector_type(8))) short s16x8;

// ---------- exact fp8 e4m3fn round-trip (RNE), matching ml_dtypes/jax ----------
__device__ __forceinline__ float qdq_e4m3(float v) {
    unsigned int u = __float_as_uint(v);
    unsigned int s = u & 0x80000000u;
    unsigned int a = u & 0x7fffffffu;
    if (a >= 0x3C800000u) {                 // |v| >= 2^-6 : normal e4m3 range
        unsigned int r = a + 0x7FFFFu + ((a >> 20) & 1u);
        r &= 0xFFF00000u;
        if (r > 0x43E00000u) r = 0x43E00000u;  // saturate at 448
        return __uint_as_float(s | r);
    } else {                                 // subnormal: grid of 2^-9
        float f = __uint_as_float(a);
        float m = rintf(f * 512.0f) * (1.0f / 512.0f);
        return __uint_as_float(s | __float_as_uint(m));
    }
}

__device__ __forceinline__ unsigned short f32_to_bf16_bits(float f) {
    unsigned int u = __float_as_uint(f);
    u += 0x7FFFu + ((u >> 16) & 1u);        // RNE
    return (unsigned short)(u >> 16);
}

// ---------- quantize x: per-row 1x64 tiles; 16 lanes per tile, float4/lane ----------
__global__ __launch_bounds__(256) void quant_x_kernel(const float* __restrict__ x,
                                                      unsigned short* __restrict__ xq,
                                                      long long n4) {
    long long g = (long long)blockIdx.x * 256 + threadIdx.x;
    if (g >= n4) return;
    f32x4 v = ((const f32x4*)x)[g];
    float a = fmaxf(fmaxf(fabsf(v.x), fabsf(v.y)), fmaxf(fabsf(v.z), fabsf(v.w)));
    a = fmaxf(a, __shfl_xor(a, 1));
    a = fmaxf(a, __shfl_xor(a, 2));
    a = fmaxf(a, __shfl_xor(a, 4));
    a = fmaxf(a, __shfl_xor(a, 8));
    float scale = fmaxf(a, 1e-12f) / 448.0f;
    ushort4 o;
    o.x = f32_to_bf16_bits(qdq_e4m3(v.x / scale) * scale);
    o.y = f32_to_bf16_bits(qdq_e4m3(v.y / scale) * scale);
    o.z = f32_to_bf16_bits(qdq_e4m3(v.z / scale) * scale);
    o.w = f32_to_bf16_bits(qdq_e4m3(v.w / scale) * scale);
    ((ushort4*)xq)[g] = o;
}

// ---------- quantize w: 64x64 blocks; one 256-thread block per weight block ----------
__global__ __launch_bounds__(256) void quant_w_kernel(const float* __restrict__ w,
                                                      unsigned short* __restrict__ wq,
                                                      int N, int K) {
    const int nb = blockIdx.y, kb = blockIdx.x;
    const int t = threadIdx.x;
    const int rgrp = t >> 4;
    const int cchk = t & 15;
    f32x4 v[4];
    float a = 0.0f;
#pragma unroll
    for (int i = 0; i < 4; ++i) {
        int row = nb * 64 + rgrp + i * 16;
        v[i] = *(const f32x4*)(w + (size_t)row * K + kb * 64 + cchk * 4);
        a = fmaxf(a, fmaxf(fmaxf(fabsf(v[i].x), fabsf(v[i].y)),
                           fmaxf(fabsf(v[i].z), fabsf(v[i].w))));
    }
#pragma unroll
    for (int off = 1; off < 64; off <<= 1) a = fmaxf(a, __shfl_xor(a, off));
    __shared__ float sm[4];
    if ((t & 63) == 0) sm[t >> 6] = a;
    __syncthreads();
    a = fmaxf(fmaxf(sm[0], sm[1]), fmaxf(sm[2], sm[3]));
    float scale = fmaxf(a, 1e-12f) / 448.0f;
#pragma unroll
    for (int i = 0; i < 4; ++i) {
        int row = nb * 64 + rgrp + i * 16;
        ushort4 o;
        o.x = f32_to_bf16_bits(qdq_e4m3(v[i].x / scale) * scale);
        o.y = f32_to_bf16_bits(qdq_e4m3(v[i].y / scale) * scale);
        o.z = f32_to_bf16_bits(qdq_e4m3(v[i].z / scale) * scale);
        o.w = f32_to_bf16_bits(qdq_e4m3(v[i].w / scale) * scale);
        *(ushort4*)(wq + (size_t)row * K + kb * 64 + cchk * 4) = o;
    }
}

// ---------- 256x256 deep-pipelined 8-phase bf16 GEMM, A[M,K] x B[N,K]^T ----------
// Region-granular staging 3-7 phases ahead, one vmcnt(4)/K-tile, tail-read of
// next tile's first fragments before the boundary barrier.
// Regions (freed-by-phase): A-mlo = rows{0-63,128-191}, A-mhi = +64;
//                           B-nlo = rows{bit5==0}, B-nhi = +32.
#define GLDS(srcp, ldsp) __builtin_amdgcn_global_load_lds( \
    (__attribute__((address_space(1))) void*)(srcp),       \
    (__attribute__((address_space(3))) void*)(ldsp), 16, 0, 0)

__global__ __launch_bounds__(512, 2) void gemm8p(const unsigned short* __restrict__ A,
                                                 const unsigned short* __restrict__ B,
                                                 const float* __restrict__ bias,
                                                 float* __restrict__ C,
                                                 int M, int N, int K) {
    __shared__ unsigned short Al[2][256 * 64];
    __shared__ unsigned short Bl[2][256 * 64];
    const int tid = threadIdx.x;
    const int wid = tid >> 6;
    const int lane = tid & 63;
    const int wm = wid >> 2, wn = wid & 3;
    const int lrow = lane & 15, kh = lane >> 4;

    // XCD-aware bijective swizzle (nwg % 8 == 0 here: 512)
    const int nbx = N >> 8;
    const int nwg = (M >> 8) * nbx;
    const int bid = blockIdx.x;
    const int swz = (bid & 7) * (nwg >> 3) + (bid >> 3);
    const int tm = swz / nbx, tn = swz % nbx;

    const unsigned short* gA = A + (size_t)tm * 256 * K;
    const unsigned short* gB = B + (size_t)tn * 256 * K;

    const int srow = lane >> 3;                       // row within 8-row segment
    const int scolb = ((lane & 7) ^ srow) << 4;       // swizzled byte col [0,128)

    const int cLo = ((kh ^ (lane & 7)) << 4);         // k-chunk kh
    const int cHi = cLo ^ 64;                         // k-chunk kh+4 (= kh^4)

    const int NT = K >> 6;

    f32x4 acc[8][4];
#pragma unroll
    for (int m = 0; m < 8; ++m)
#pragma unroll
        for (int n = 0; n < 4; ++n) acc[m][n] = (f32x4){0.f, 0.f, 0.f, 0.f};

    s16x8 af[4][2], bf[2][2];

    // stage one A-region (2 GLDS/wave): mhalf 0 -> rows{0-63,128-191}, 1 -> +64
    auto STGA = [&](int mhalf, int t, int bufn) {
#pragma unroll
        for (int i = 0; i < 2; ++i) {
            int j = wid + i * 8;
            int row = ((j & 7) << 3) + ((j >> 3) << 7) + (mhalf << 6);
            GLDS((const char*)gA + ((size_t)(row + srow) * K + (size_t)t * 64) * 2 + scolb,
                 (char*)&Al[bufn][0] + row * 128);
        }
    };
    // stage one B-region: nhalf 0 -> rows{bit5==0}, 1 -> +32
    auto STGB = [&](int nhalf, int t, int bufn) {
#pragma unroll
        for (int i = 0; i < 2; ++i) {
            int j = wid + i * 8;
            int row = ((j & 3) << 3) + ((j >> 2) << 6) + (nhalf << 5);
            GLDS((const char*)gB + ((size_t)(row + srow) * K + (size_t)t * 64) * 2 + scolb,
                 (char*)&Bl[bufn][0] + row * 128);
        }
    };

    auto READ_PH0 = [&](const char* pA_, const char* pB_) {   // 12 ds_read_b128
#pragma unroll
        for (int m = 0; m < 4; ++m) {
            af[m][0] = *(const s16x8*)(pA_ + m * 2048 + cLo);
            af[m][1] = *(const s16x8*)(pA_ + m * 2048 + cHi);
        }
#pragma unroll
        for (int n = 0; n < 2; ++n) {
            bf[n][0] = *(const s16x8*)(pB_ + n * 2048 + cLo);
            bf[n][1] = *(const s16x8*)(pB_ + n * 2048 + cHi);
        }
    };

    auto MM = [&](int mo, int no) {
#pragma unroll
        for (int m = 0; m < 4; ++m)
#pragma unroll
            for (int n = 0; n < 2; ++n) {
                acc[m + mo][n + no] = __builtin_amdgcn_mfma_f32_16x16x32_bf16(af[m][0], bf[n][0], acc[m + mo][n + no], 0, 0, 0);
                acc[m + mo][n + no] = __builtin_amdgcn_mfma_f32_16x16x32_bf16(af[m][1], bf[n][1], acc[m + mo][n + no], 0, 0, 0);
            }
    };

    const char* pAb[2] = {(const char*)&Al[0][0] + ((wm << 7) + lrow) * 128,
                          (const char*)&Al[1][0] + ((wm << 7) + lrow) * 128};
    const char* pBb[2] = {(const char*)&Bl[0][0] + ((wn << 6) + lrow) * 128,
                          (const char*)&Bl[1][0] + ((wn << 6) + lrow) * 128};

    // ---- prologue: buf0 full (8 loads) + buf1 A-mlo/B-nhi/A-mhi (6 loads)
    STGA(0, 0, 0); STGB(0, 0, 0); STGB(1, 0, 0); STGA(1, 0, 0);
    STGA(0, 1, 1); STGB(1, 1, 1); STGA(1, 1, 1);
    asm volatile("s_waitcnt vmcnt(6)" ::: "memory");
    asm volatile("s_barrier" ::: "memory");
    READ_PH0(pAb[0], pBb[0]);

    auto TILE = [&](int buf, int t) {
        const char* pA  = pAb[buf];
        const char* pB  = pBb[buf];
        const char* pAn = pAb[buf ^ 1];
        const char* pBn = pBb[buf ^ 1];
        int t1 = t + 1; if (t1 >= NT) t1 -= NT;
        int t2 = t + 2; if (t2 >= NT) t2 -= NT;

        // ---- ph0: stage B-nlo(t+1 -> buf'), wait own frags, MFMA m0-3 x n0-1
        STGB(0, t1, buf ^ 1);
        asm volatile("s_waitcnt lgkmcnt(0)" ::: "memory");
        __builtin_amdgcn_sched_barrier(0);
        __builtin_amdgcn_s_setprio(1);
        MM(0, 0);
        __builtin_amdgcn_s_setprio(0);
        asm volatile("s_barrier" ::: "memory");

        // ---- ph1: read bf n2-3, stage A-mlo(t+2 -> buf), MFMA m0-3 x n2-3
#pragma unroll
        for (int n = 0; n < 2; ++n) {
            bf[n][0] = *(const s16x8*)(pB + (n + 2) * 2048 + cLo);
            bf[n][1] = *(const s16x8*)(pB + (n + 2) * 2048 + cHi);
        }
        STGA(0, t2, buf);
        asm volatile("s_barrier" ::: "memory");
        asm volatile("s_waitcnt lgkmcnt(0)" ::: "memory");
        __builtin_amdgcn_sched_barrier(0);
        __builtin_amdgcn_s_setprio(1);
        MM(0, 2);
        __builtin_amdgcn_s_setprio(0);
        asm volatile("s_barrier" ::: "memory");

        // ---- ph2: read af m4-7, stage B-nhi(t+2 -> buf), MFMA m4-7 x n2-3, drain
#pragma unroll
        for (int m = 0; m < 4; ++m) {
            af[m][0] = *(const s16x8*)(pA + (m + 4) * 2048 + cLo);
            af[m][1] = *(const s16x8*)(pA + (m + 4) * 2048 + cHi);
        }
        STGB(1, t2, buf);
        asm volatile("s_barrier" ::: "memory");
        asm volatile("s_waitcnt lgkmcnt(0)" ::: "memory");
        __builtin_amdgcn_sched_barrier(0);
        __builtin_amdgcn_s_setprio(1);
        MM(4, 2);
        __builtin_amdgcn_s_setprio(0);
        asm volatile("s_waitcnt vmcnt(4)" ::: "memory");   // buf' fully staged (>=2 phases old)
        asm volatile("s_barrier" ::: "memory");

        // ---- ph3: read bf n0-1, stage A-mhi(t+2 -> buf), MFMA m4-7 x n0-1,
        //           then tail-read next tile's ph0 fragments from buf'
#pragma unroll
        for (int n = 0; n < 2; ++n) {
            bf[n][0] = *(const s16x8*)(pB + n * 2048 + cLo);
            bf[n][1] = *(const s16x8*)(pB + n * 2048 + cHi);
        }
        STGA(1, t2, buf);
        asm volatile("s_barrier" ::: "memory");
        asm volatile("s_waitcnt lgkmcnt(0)" ::: "memory");
        __builtin_amdgcn_sched_barrier(0);
        __builtin_amdgcn_s_setprio(1);
        MM(4, 0);
        __builtin_amdgcn_s_setprio(0);
        READ_PH0(pAn, pBn);
        asm volatile("s_barrier" ::: "memory");
    };

    for (int t = 0; t < NT; t += 2) {
        TILE(0, t);
        TILE(1, t + 1);
    }

    // epilogue: C/D layout col=lane&15, row=(lane>>4)*4+j
    const int gcol0 = tn * 256 + wn * 64 + lrow;
    const int grow0 = tm * 256 + wm * 128 + (lane >> 4) * 4;
#pragma unroll
    for (int n = 0; n < 4; ++n) {
        float bv = bias[gcol0 + n * 16];
#pragma unroll
        for (int m = 0; m < 8; ++m) {
#pragma unroll
            for (int j = 0; j < 4; ++j) {
                unsigned short b = f32_to_bf16_bits(acc[m][n][j]);
                C[(size_t)(grow0 + m * 16 + j) * N + gcol0 + n * 16] =
                    __uint_as_float(((unsigned int)b) << 16) + bv;
            }
        }
    }
}

extern "C" void kernel_launch(void* const* d_in, const int* in_sizes, int n_in,
                              void* d_out, int out_size, void* d_ws, size_t ws_size,
                              hipStream_t stream) {
    const float* x    = (const float*)d_in[0];
    const float* w    = (const float*)d_in[1];
    const float* bias = (const float*)d_in[2];
    float* out = (float*)d_out;

    const int N = in_sizes[2];
    const long long KL = (long long)in_sizes[1] / N;
    const int K = (int)KL;
    const int M = (int)((long long)in_sizes[0] / KL);

    unsigned short* xq = (unsigned short*)d_ws;
    unsigned short* wq = xq + (size_t)M * K;

    long long n4 = (long long)M * K / 4;
    quant_x_kernel<<<(unsigned)((n4 + 255) / 256), 256, 0, stream>>>(x, xq, n4);

    dim3 gw(K / 64, N / 64);
    quant_w_kernel<<<gw, 256, 0, stream>>>(w, wq, N, K);

    const int nwg = (M / 256) * (N / 256);
    gemm8p<<<nwg, 512, 0, stream>>>(xq, wq, bias, out, M, N, K);
}